// Round 5
// baseline (265.825 us; speedup 1.0000x reference)
//
#include <hip/hip_runtime.h>

#define B 8
#define K 16
#define H 224
#define W 224
#define PH 232
#define PW 232
#define WIN 9
#define NP (B * H * W)            // 401408 pixels

typedef float vf4 __attribute__((ext_vector_type(4), aligned(4)));
typedef float vf4a __attribute__((ext_vector_type(4)));

// ---------------- Kernel M: direct-weight, reg-double-buffered ----------------
// Block: 256 thr = q(8) x kg(4) x rr(8 rows); tile = 8 out-rows x 32 px x 16 k.
// Thread: 4 px x 4 k x 1 out-row.
// R4 lesson (VGPR=76, 12.7k cyc/iter): compiler serialized the 12 weight loads
// per iteration -> 12 back-to-back memory latencies. Fix: register
// double-buffer the weight batch (wA/wB ping-pong, fully unrolled m loop,
// static indices only), issue batch m+1 BEFORE the FMA block of m, pinned by
// sched_barrier(0). Weight loads are 16B-aligned dwordx4 via aligned-window +
// compile-time rotation: floats [81p+9m .. +8] live in 3 vf4a at base
// (81p+9m)&~3 with rot=(p+m)&3 (81==9==1 mod 4).
// LDS: 16 padded k-planes, row stride 44, plane stride 708.
#define PSTR 708                              // 16 rows * 44 + 4 pad
#define RSTR 44

// load the 12 aligned float4s covering weight taps of row m_ for 4 px
#define LOADW(dst, m_) do {                                                  \
    _Pragma("unroll")                                                        \
    for (int p = 0; p < 4; ++p) {                                            \
        const int off = 81 * p + 9 * (m_);                                   \
        const int fb  = off & ~3;                                            \
        dst[3*p+0] = *(const vf4a*)(wb + fb);                                \
        dst[3*p+1] = *(const vf4a*)(wb + fb + 4);                            \
        dst[3*p+2] = *(const vf4a*)(wb + fb + 8);                            \
    }                                                                        \
} while (0)

// consume weight batch src (taps of row m_) against LDS window rows
#define CONS(src, m_) do {                                                   \
    _Pragma("unroll")                                                        \
    for (int kk = 0; kk < 4; ++kk) {                                         \
        const float* lb = &pad_lds[(kg*4+kk)*PSTR + (rr+(m_))*RSTR + 4*q];   \
        vf4a a0 = *(const vf4a*)lb;                                          \
        vf4a a1 = *(const vf4a*)(lb + 4);                                    \
        vf4a a2 = *(const vf4a*)(lb + 8);                                    \
        float wk[12];                                                        \
        _Pragma("unroll")                                                    \
        for (int p2 = 0; p2 < 4; ++p2) {                                     \
            wk[p2]     = ((const float*)&a0)[p2];                            \
            wk[p2 + 4] = ((const float*)&a1)[p2];                            \
            wk[p2 + 8] = ((const float*)&a2)[p2];                            \
        }                                                                    \
        _Pragma("unroll")                                                    \
        for (int p = 0; p < 4; ++p) {                                        \
            const int rot = (81 * p + 9 * (m_)) & 3;                         \
            _Pragma("unroll")                                                \
            for (int n = 0; n < 9; ++n) {                                    \
                const int ci = rot + n;                                      \
                acc[kk][p] = fmaf(wk[p + n],                                 \
                    ((const float*)&src[3*p + (ci >> 2)])[ci & 3],           \
                    acc[kk][p]);                                             \
            }                                                                \
        }                                                                    \
    }                                                                        \
} while (0)

__global__ __launch_bounds__(256, 3) void ncuts_dw(
    const float* __restrict__ seg,
    const float* __restrict__ padded,
    const float* __restrict__ weight,
    const float* __restrict__ sumw,
    float* __restrict__ ws)
{
    __shared__ float pad_lds[16 * PSTR];      // 45.3 KB
    __shared__ float red[4][16][2];

    const int tid = threadIdx.x;
    const int bid = blockIdx.x;               // b + 8*(wt + 7*ht)
    const int b   = bid & 7;                  // XCD x owns batch b
    const int rest = bid >> 3;                // 0..195
    const int ht  = rest / 7;
    const int wt  = rest - ht * 7;
    const int h0 = ht * 8, w0 = wt * 32;

    // ---- stage padded: 16 planes x 16 rows x 40 floats (stride 44) ----
#pragma unroll
    for (int i = 0; i < 10; ++i) {
        const int f   = tid + 256 * i;        // < 2560 float4s
        const int k   = f / 160;
        const int rem = f - k * 160;
        const int r   = rem / 10;
        const int c   = rem - r * 10;
        vf4a v = *(const vf4a*)(padded +
            (((long)(b * K + k) * PH + (h0 + r)) * PW + (w0 + 4 * c)));
        *(vf4a*)&pad_lds[k * PSTR + r * RSTR + 4 * c] = v;
    }
    __syncthreads();

    const int lane = tid & 63;
    const int q    = lane & 7;                // px group (4 px)
    const int kg   = (lane >> 3) & 3;         // k quad
    const int rr   = tid >> 5;                // 0..7 out-row
    const int h    = h0 + rr;
    const long pix0 = (long)(b * H + h) * W + w0 + 4 * q;
    const float* wb = weight + pix0 * 81;     // 16B-aligned (pix0 % 4 == 0)

    float acc[4][4];                          // [kk][p]
#pragma unroll
    for (int kk = 0; kk < 4; ++kk)
#pragma unroll
        for (int p = 0; p < 4; ++p) acc[kk][p] = 0.f;

    vf4a wA[12], wB[12];
    LOADW(wA, 0);                             // prologue: batch m=0
#pragma unroll
    for (int m = 0; m < 9; ++m) {
        if (m < 8) {                          // prefetch batch m+1
            if (m & 1) LOADW(wA, m + 1);
            else       LOADW(wB, m + 1);
        }
        __builtin_amdgcn_sched_barrier(0);    // keep prefetch above the FMAs
        if (m & 1) CONS(wB, m);
        else       CONS(wA, m);
    }

    // ---- epilogue: assocA/assocV partials (1 row, 4 px, 4 k) ----
    float aA[4], aV[4];
    {
        const vf4a sw4 = __builtin_nontemporal_load((const vf4a*)(sumw + pix0));
#pragma unroll
        for (int kk = 0; kk < 4; ++kk) {
            const int k = kg * 4 + kk;
            const float* sp = seg + ((long)(b * K + k) * H + h) * W + w0 + 4 * q;
            const vf4a s4 = __builtin_nontemporal_load((const vf4a*)sp);
            float a = 0.f, v = 0.f;
#pragma unroll
            for (int p = 0; p < 4; ++p) {
                a = fmaf(acc[kk][p], ((const float*)&s4)[p], a);
                v = fmaf(((const float*)&sw4)[p], ((const float*)&s4)[p], v);
            }
            aA[kk] = a; aV[kk] = v;
        }
    }
    // reduce over q (lane bits 0-2) and row-parity (bit 5); kg lanes survive
#pragma unroll
    for (int off = 0; off < 4; ++off) {
        const int d = (off < 3) ? (1 << off) : 32;
#pragma unroll
        for (int kk = 0; kk < 4; ++kk) {
            aA[kk] += __shfl_xor(aA[kk], d);
            aV[kk] += __shfl_xor(aV[kk], d);
        }
    }
    const int wv = tid >> 6;
    if ((lane & 39) == 0) {                   // lanes 0,8,16,24
#pragma unroll
        for (int kk = 0; kk < 4; ++kk) {
            red[wv][kg * 4 + kk][0] = aA[kk];
            red[wv][kg * 4 + kk][1] = aV[kk];
        }
    }
    __syncthreads();
    if (tid < 32) {
        const int k  = tid >> 1;
        const int ab = tid & 1;
        const float v = red[0][k][ab] + red[1][k][ab] + red[2][k][ab] + red[3][k][ab];
        atomicAdd(&ws[ab * 128 + b * 16 + k], v);
    }
}

__global__ void ncuts_final(const float* __restrict__ ws,
                            const int* __restrict__ ncut_k,
                            float* __restrict__ out)
{
    const int t = threadIdx.x;          // 128 threads: t = b*16 + k
    const int b = t >> 4;
    const int k = t & 15;
    float r = ws[b * K + k] / ws[128 + b * K + k];
#pragma unroll
    for (int off = 1; off < 16; off <<= 1) r += __shfl_xor(r, off, 16);
    if (k == 0) out[b] = (float)(*ncut_k) - r;
}

extern "C" void kernel_launch(void* const* d_in, const int* in_sizes, int n_in,
                              void* d_out, int out_size, void* d_ws, size_t ws_size,
                              hipStream_t stream) {
    (void)in_sizes; (void)n_in; (void)out_size; (void)ws_size;
    const float* seg    = (const float*)d_in[0];
    const float* padded = (const float*)d_in[1];
    const float* weight = (const float*)d_in[2];
    const float* sumw   = (const float*)d_in[3];
    const int*   nk     = (const int*)d_in[5];
    float* ws  = (float*)d_ws;
    float* out = (float*)d_out;

    hipMemsetAsync(ws, 0, 2 * B * K * sizeof(float), stream);
    ncuts_dw<<<8 * 28 * 7, 256, 0, stream>>>(seg, padded, weight, sumw, ws);
    ncuts_final<<<1, 128, 0, stream>>>(ws, nk, out);
}